// Round 6
// baseline (47.767 us; speedup 1.0000x reference)
//
#include <hip/hip_runtime.h>
#include <math.h>
#include <type_traits>

#define QDEPTH 10
#define WIRES 10
#define NSTATE 1024
#define NGATES (QDEPTH * WIRES)

typedef float f2 __attribute__((ext_vector_type(2)));

// ---------------------------------------------------------------------------
// Layout: stored index s = w<<8 | j<<6 | lane (w: 2 wave bits, j: 2 reg bits).
// Wire q <-> bit (9-q): wires 0,1 -> wave bits (folded into CNOT gather);
// wires 2,3 -> reg bits; wires 4-9 -> lane bits 5..0 (shfl_xor).
// LDS: interleaved f2 amp at pair-index swz(s) = s ^ ((s>>5)&31)  (<=2-way).
// ---------------------------------------------------------------------------
constexpr unsigned sigma_apply(int q, int r, unsigned i) {
    int cb = 9 - q, tb = 9 - ((q + r) % 10);
    return i ^ (((i >> cb) & 1u) << tb);
}
constexpr unsigned G_apply(int l, unsigned i) {
    int r = (l % 9) + 1;
    for (int q = 9; q >= 0; --q) i = sigma_apply(q, r, i);  // G = s0∘s1∘…∘s9
    return i;
}
constexpr unsigned swz(unsigned w) { return w ^ ((w >> 5) & 31u); }

struct U2 { unsigned x, y; };
struct P2 { U2 t[QDEPTH][256]; };        // 4 packed u16 targets per (w,lane)
constexpr P2 make_perm2() {
    P2 p{};
    for (int l = 0; l < QDEPTH; ++l)
        for (unsigned wl = 0; wl < 256; ++wl) {
            unsigned w = wl >> 6, lane = wl & 63u;
            unsigned t0 = swz(G_apply(l, (w << 8) | (0u << 6) | lane));
            unsigned t1 = swz(G_apply(l, (w << 8) | (1u << 6) | lane));
            unsigned t2 = swz(G_apply(l, (w << 8) | (2u << 6) | lane));
            unsigned t3 = swz(G_apply(l, (w << 8) | (3u << 6) | lane));
            p.t[l][wl].x = t0 | (t1 << 16);
            p.t[l][wl].y = t2 | (t3 << 16);
        }
    return p;
}
__constant__ P2 PERM2 = make_perm2();

template <int N, int I = 0, typename F>
__device__ __forceinline__ void static_for(F&& f) {
    if constexpr (I < N) {
        f(std::integral_constant<int, I>{});
        static_for<N, I + 1>(f);
    }
}

__device__ __forceinline__ float fxor(float a, unsigned s) {
    return __uint_as_float(__float_as_uint(a) ^ s);
}
__device__ __forceinline__ f2 fxor2(f2 a, unsigned s) {
    f2 r; r.x = fxor(a.x, s); r.y = fxor(a.y, s); return r;
}
__device__ __forceinline__ f2 swap2(f2 a) { return __builtin_shufflevector(a, a, 1, 0); }
__device__ __forceinline__ f2 pkfma(f2 a, f2 b, f2 c) {
    return __builtin_elementwise_fma(a, b, c);
}

// ---------------------------------------------------------------------------
// Kernel 1: 100 Rot gates -> packed coefficient pairs per gate (8 floats):
// (Ar,Ar), (-Ai,Ai), (Br,Br), (-Bi,Bi)   [SU(2): rows differ by negation only]
// ---------------------------------------------------------------------------
__global__ void gates_kernel(const float* __restrict__ w, float* __restrict__ g) {
    int i = threadIdx.x;
    if (i >= NGATES) return;
    float phi = tanhf(w[3 * i + 0]);
    float th  = tanhf(w[3 * i + 1]);
    float om  = tanhf(w[3 * i + 2]);
    float c = cosf(0.5f * th), s = sinf(0.5f * th);
    float a = 0.5f * (phi + om), d = 0.5f * (phi - om);
    float Ar =  cosf(a) * c, Ai = -sinf(a) * c;    // g00
    float Br = -cosf(d) * s, Bi = -sinf(d) * s;    // g01
    float* p = g + 8 * i;
    p[0] = Ar;  p[1] = Ar;
    p[2] = -Ai; p[3] = Ai;
    p[4] = Br;  p[5] = Br;
    p[6] = -Bi; p[7] = Bi;
}

// Reg-bit gate: pairs (j, j|1<<JB); row0 for j, row1 for jp; pure pk-FMA.
template <int JB>
__device__ __forceinline__ void apply_gate_reg(f2 (&s)[4], const f2* __restrict__ gp) {
    const f2 ArP = gp[0], AiSW = gp[1], BrP = gp[2], BiSW = gp[3];
    static_for<2>([&](auto P) {
        constexpr int p  = P.value;
        constexpr int lo = p & ((1 << JB) - 1);
        constexpr int j  = ((p & ~((1 << JB) - 1)) << 1) | lo;
        constexpr int jp = j | (1 << JB);
        f2 a = s[j], b = s[jp];
        f2 as = swap2(a), bs = swap2(b);
        f2 n0 = a * ArP;                 // row0: A*a + B*b
        n0 = pkfma(AiSW, as, n0);
        n0 = pkfma(BrP,  b,  n0);
        n0 = pkfma(BiSW, bs, n0);
        f2 n1 = a * (-BrP);              // row1: -conj(B)*a + conj(A)*b
        n1 = pkfma(BiSW,  as, n1);
        n1 = pkfma(ArP,   b,  n1);
        n1 = pkfma(-AiSW, bs, n1);
        s[j] = n0; s[jp] = n1;
    });
}

// ---------------------------------------------------------------------------
// Kernel 2: 4 waves per batch element; 4 packed complex amps per thread.
// ---------------------------------------------------------------------------
__global__ __launch_bounds__(256) void sim_kernel(const float* __restrict__ x,
                                                  const float* __restrict__ gtab,
                                                  float* __restrict__ out) {
    __shared__ f2 buf[2][NSTATE];        // interleaved (re,im), 16 KB
    __shared__ f2 glds[NGATES * 4];      // packed gate records, 3.2 KB
    __shared__ float wsum[4];
    const int b    = blockIdx.x;
    const int tid  = threadIdx.x;
    const int w    = tid >> 6;
    const int lane = tid & 63;
    const int whi  = w << 8;
    const float* xb = x + (size_t)b * NSTATE;

    // stage gate records once
    for (int i = tid; i < NGATES * 4; i += 256)
        glds[i] = ((const f2*)gtab)[i];

    f2 s[4];

    // ---- amplitude embedding + cross-wave L2 normalize ----
    float ss = 0.f;
    static_for<4>([&](auto J) {
        constexpr int j = J.value;
        float v = xb[whi | (j << 6) | lane];
        s[j].x = v; s[j].y = 0.f;
        ss = fmaf(v, v, ss);
    });
#pragma unroll
    for (int off = 1; off < 64; off <<= 1) ss += __shfl_xor(ss, off);
    if (lane == 0) wsum[w] = ss;
    __syncthreads();
    const float nrm = 1.0f / sqrtf(wsum[0] + wsum[1] + wsum[2] + wsum[3]);
    static_for<4>([&](auto J) { s[J.value] *= nrm; });

#pragma unroll 1
    for (int l = 0; l < QDEPTH; ++l) {
        f2* bufc = buf[l & 1];
        const f2* gl = glds + 40 * l;

        // prefetch packed gather targets (one dwordx2)
        const U2 e = PERM2.t[l][tid];
        unsigned tarr[4] = { e.x & 0xFFFFu, e.x >> 16, e.y & 0xFFFFu, e.y >> 16 };

        // ---- wires 2,3 on reg bits 1,0 (pure pk-FMA) ----
        apply_gate_reg<1>(s, gl + 4 * 2);
        apply_gate_reg<0>(s, gl + 4 * 3);

        // ---- wires 4..9 on lane bits 5..0 (shuffles, no barrier) ----
        static_for<6>([&](auto Q) {
            constexpr int qq = Q.value;               // wire 4+qq
            constexpr int m  = 1 << (5 - qq);
            const f2* gp = gl + 4 * (4 + qq);
            const f2 ArP = gp[0], BiSW = gp[3];
            const unsigned sm = (lane & m) ? 0x80000000u : 0u;
            const f2 c2 = fxor2(gp[1], sm);           // ±AiSW
            const f2 c3 = fxor2(gp[2], sm);           // ±BrP
            static_for<4>([&](auto J) {
                constexpr int j = J.value;
                f2 a = s[j];
                f2 p; p.x = __shfl_xor(a.x, m); p.y = __shfl_xor(a.y, m);
                f2 n = a * ArP;
                n = pkfma(c2, swap2(a), n);
                n = pkfma(c3, p, n);
                n = pkfma(BiSW, swap2(p), n);
                s[j] = n;
            });
        });

        // ---- write state to LDS (b64, swizzled; <=2-way) ----
        static_for<4>([&](auto J) {
            constexpr int j = J.value;
            int si = whi | (j << 6) | lane;
            bufc[si ^ ((si >> 5) & 31)] = s[j];
        });
        __syncthreads();

        // ---- wires 0,1 (bits 9,8) folded into CNOT gather (4 b64 reads) ----
        const float Er = gl[0].x, Ei = gl[1].y, Fr = gl[2].x, Fi = gl[3].y; // wire0
        const float Cr = gl[4].x, Ci = gl[5].y, Dr = gl[6].x, Di = gl[7].y; // wire1
        static_for<4>([&](auto J) {
            constexpr int j = J.value;
            unsigned t0 = tarr[j];
            unsigned sgn8 = (t0 & 256u) << 23;        // bit8 -> sign bit
            unsigned sgn9 = (t0 & 512u) << 22;        // bit9 -> sign bit
            f2 v0 = bufc[t0];
            f2 v1 = bufc[t0 ^ 264u];                  // swz(p^256)
            f2 v2 = bufc[t0 ^ 528u];                  // swz(p^512)
            f2 v3 = bufc[t0 ^ 792u];                  // swz(p^768)
            float Cis = fxor(Ci, sgn8), Drs = fxor(Dr, sgn8);
            float Eis = fxor(Ei, sgn9), Frs = fxor(Fr, sgn9);
            float isr = fmaf(Cr, v0.x, fmaf(-Cis, v0.y, fmaf(Drs, v1.x, -Di * v1.y)));
            float isi = fmaf(Cr, v0.y, fmaf( Cis, v0.x, fmaf(Drs, v1.y,  Di * v1.x)));
            float ipr = fmaf(Cr, v2.x, fmaf(-Cis, v2.y, fmaf(Drs, v3.x, -Di * v3.y)));
            float ipi = fmaf(Cr, v2.y, fmaf( Cis, v2.x, fmaf(Drs, v3.y,  Di * v3.x)));
            f2 n;
            n.x = fmaf(Er, isr, fmaf(-Eis, isi, fmaf(Frs, ipr, -Fi * ipi)));
            n.y = fmaf(Er, isi, fmaf( Eis, isr, fmaf(Frs, ipi,  Fi * ipr)));
            s[j] = n;
        });
        // no trailing barrier: next layer writes the other buffer
    }

    // ---- probs = clip(|amp|^2 * 1024, 0, 1); layout already logical ----
    float* ob = out + (size_t)b * NSTATE;
    static_for<4>([&](auto J) {
        constexpr int j = J.value;
        float p = fmaf(s[j].x, s[j].x, s[j].y * s[j].y) * (float)NSTATE;
        ob[whi | (j << 6) | lane] = fminf(p, 1.0f);
    });
}

extern "C" void kernel_launch(void* const* d_in, const int* in_sizes, int n_in,
                              void* d_out, int out_size, void* d_ws, size_t ws_size,
                              hipStream_t stream) {
    const float* x = (const float*)d_in[0];   // [1024,1,32,32] f32
    const float* w = (const float*)d_in[1];   // [10,10,3] f32
    float* out   = (float*)d_out;             // [1024,1,32,32] f32
    float* gates = (float*)d_ws;              // 100*8 floats scratch

    gates_kernel<<<1, 128, 0, stream>>>(w, gates);
    sim_kernel<<<1024, 256, 0, stream>>>(x, gates, out);
}